// Round 14
// baseline (73.571 us; speedup 1.0000x reference)
//
#include <hip/hip_runtime.h>

// Chamfer loss: B=4, N=M=8192, D=3, fp32 in, scalar fp32 out.
// loss = mean_n min_m ||x_n-y_m||^2 + mean_m min_n ||...||^2 + lambda*bpp
//
// R13 = R12's verified loop structure (4-tile prefetch groups, paired
// v_min3 merge, <=2 acc tiles live at once — R12 proved this safe) +
// 2 A-fragments per wave to HALVE B-fragment delivery (536->268 MB),
// which R12's null results isolated as the dominant term (~13.7us of
// VMEM delivery vs 6.8us merge + 1.7us MFMA). Per B pair (P0,P1):
//   acc0=mfma(A0,P0); acc1=mfma(A0,P1); racc0=min3(acc0,acc1,racc0)
//   acc0=mfma(A1,P0); acc1=mfma(A1,P1); racc1=min3(acc0,acc1,racc1)
// Wave owns 64 rows x 2048-col segment (NSEG=4), grid 1024, 4096 waves.
// Indexing identical to R9 (verified bit-exact); R9's confounds
// (unroll-1 pragma, 2-tile prefetch) removed.
// Math (bit-exact since R6): P = y2 - 2 x.y via one 32x32x16 per tile:
//   k0-2: -2xhi*yhi  k3: 1*y2hi  k4-6: -2xlo*yhi  k7: 1*y2lo
//   k8-10: -2xhi*ylo k11-15: 0
// A/B frag: row/col = lane&31, k-octet = lane>>5.
// C/D: col = lane&31, row = (q&3)+8*(q>>2)+4*(lane>>5).

typedef float  f16v __attribute__((ext_vector_type(16)));
typedef short  s8   __attribute__((ext_vector_type(8)));

#define NPTS   8192
#define NB     4
#define NPTOT  (NB * NPTS)        // 32768 points per cloud
#define NSEG   4                  // column-segment split (2048 cols each)
#define RBLK   128

__device__ __forceinline__ ushort f2bf(float f) {
    uint u = __float_as_uint(f);
    u += 0x7FFF + ((u >> 16) & 1);          // round-to-nearest-even
    return (ushort)(u >> 16);
}
__device__ __forceinline__ float bf2f(ushort h) {
    return __uint_as_float(((uint)h) << 16);
}
__device__ __forceinline__ uint pk(ushort lo, ushort hi) {
    return (uint)lo | ((uint)hi << 16);
}

// prep: per point (both clouds): split coords and ||p||^2 into bf16 hi/lo,
// store A-side records (rows) and B-side records (cols), 2 x uint4 each.
__global__ __launch_bounds__(256) void prep(
        const float* __restrict__ X, const float* __restrict__ Y,
        uint4* __restrict__ Arec, uint4* __restrict__ Brec) {
    int i = blockIdx.x * 256 + threadIdx.x;
    if (i >= 2 * NPTOT) return;
    const float* src = (i < NPTOT) ? X : Y;
    int p = i & (NPTOT - 1);
    float x0 = src[3*p], x1 = src[3*p+1], x2 = src[3*p+2];
    float n2 = __fmaf_rn(x0, x0, __fmaf_rn(x1, x1, x2 * x2));

    ushort h0 = f2bf(x0), h1 = f2bf(x1), h2 = f2bf(x2);
    ushort l0 = f2bf(x0 - bf2f(h0));
    ushort l1 = f2bf(x1 - bf2f(h1));
    ushort l2 = f2bf(x2 - bf2f(h2));
    ushort n2h = f2bf(n2);
    ushort n2l = f2bf(n2 - bf2f(n2h));
    ushort a0 = f2bf(-2.0f * bf2f(h0)), a1 = f2bf(-2.0f * bf2f(h1));
    ushort a2 = f2bf(-2.0f * bf2f(h2));
    ushort b0 = f2bf(-2.0f * bf2f(l0)), b1 = f2bf(-2.0f * bf2f(l1));
    ushort b2 = f2bf(-2.0f * bf2f(l2));
    const ushort ONE = 0x3F80;

    Arec[(size_t)i*2 + 0] = make_uint4(pk(a0,a1), pk(a2,ONE), pk(b0,b1), pk(b2,ONE));
    Arec[(size_t)i*2 + 1] = make_uint4(pk(a0,a1), pk(a2,0),   0,          0);
    Brec[(size_t)i*2 + 0] = make_uint4(pk(h0,h1), pk(h2,n2h), pk(h0,h1), pk(h2,n2l));
    Brec[(size_t)i*2 + 1] = make_uint4(pk(l0,l1), pk(l2,0),   0,          0);
}

#define LOADG(G, g)                                                        \
    _Pragma("unroll")                                                      \
    for (int u = 0; u < 4; u++)                                            \
        G[u] = *(const s8*)(Bseg + (size_t)((g) * 4 + u) * 64 + boff);

// per 4-tile group: 2 pairs; per pair 4 MFMAs sequenced through 2 accs
#define COMPG(G)                                                           \
    _Pragma("unroll")                                                      \
    for (int u = 0; u < 4; u += 2) {                                       \
        f16v acc0 = __builtin_amdgcn_mfma_f32_32x32x16_bf16(               \
            A0, G[u], zero16, 0, 0, 0);                                    \
        f16v acc1 = __builtin_amdgcn_mfma_f32_32x32x16_bf16(               \
            A0, G[u + 1], zero16, 0, 0, 0);                                \
        _Pragma("unroll")                                                  \
        for (int q = 0; q < 16; q++)                                       \
            racc0[q] = fminf(fminf(acc0[q], acc1[q]), racc0[q]);           \
        f16v acc2 = __builtin_amdgcn_mfma_f32_32x32x16_bf16(               \
            A1, G[u], zero16, 0, 0, 0);                                    \
        f16v acc3 = __builtin_amdgcn_mfma_f32_32x32x16_bf16(               \
            A1, G[u + 1], zero16, 0, 0, 0);                                \
        _Pragma("unroll")                                                  \
        for (int q = 0; q < 16; q++)                                       \
            racc1[q] = fminf(fminf(acc2[q], acc3[q]), racc1[q]);           \
    }

__global__ __launch_bounds__(256) void mfma_pass(
        const uint4* __restrict__ Arec, const uint4* __restrict__ Brec,
        float* __restrict__ minsP) {
    // grid = 1024: pass(2) x batch(4) x rowblk(32) x seg(4)
    // block = 4 waves; wave owns 64 rows x one 2048-col segment
    int bid    = blockIdx.x;
    int pass   = bid >> 9;
    int r      = bid & 511;
    int b      = r >> 7;
    int rem    = r & 127;
    int rowblk = rem >> 2;
    int seg    = rem & 3;
    int lane   = threadIdx.x & 63;
    int wave   = threadIdx.x >> 6;
    int ca     = pass;              // A-cloud: 0=X,1=Y
    int cb     = 1 - pass;
    int rowbase = rowblk * 256 + wave * 64;

    // two A fragments: rows [rowbase,+32) and [rowbase+32,+64)
    size_t pA = (size_t)ca * NPTOT + (size_t)b * NPTS + rowbase + (lane & 31);
    int krec = lane >> 5;
    s8 A0 = *(const s8*)&Arec[(pA)      * 2 + krec];
    s8 A1 = *(const s8*)&Arec[(pA + 32) * 2 + krec];

    // B segment: 2048 points = 64 col-tiles (64 recs of 16B each)
    const uint4* Bseg = Brec + ((size_t)cb * NPTOT + (size_t)b * NPTS
                      + (size_t)seg * 2048) * 2;
    int boff = (lane & 31) * 2 + krec;

    const f16v zero16 = {0,0,0,0,0,0,0,0,0,0,0,0,0,0,0,0};
    f16v racc0, racc1;
#pragma unroll
    for (int q = 0; q < 16; q++) { racc0[q] = 3.0e38f; racc1[q] = 3.0e38f; }

    // 16 groups of 4 col-tiles, ping-pong prefetch
    s8 GA[4], GB[4];
    LOADG(GA, 0);
    for (int g = 0; g < 14; g += 2) {
        LOADG(GB, g + 1);
        COMPG(GA);
        LOADG(GA, g + 2);
        COMPG(GB);
    }
    LOADG(GB, 15);
    COMPG(GA);
    COMPG(GB);

    // row-min across 32 cols (lane bits 0-4), plain store per segment
    float* dst = minsP + ((size_t)seg * 2 + pass) * NPTOT + (size_t)b * NPTS;
    int half = lane >> 5;
#pragma unroll
    for (int h2 = 0; h2 < 2; h2++) {
#pragma unroll
        for (int q = 0; q < 16; q++) {
            float v = h2 ? racc1[q] : racc0[q];
            v = fminf(v, __shfl_xor(v, 1, 64));
            v = fminf(v, __shfl_xor(v, 2, 64));
            v = fminf(v, __shfl_xor(v, 4, 64));
            v = fminf(v, __shfl_xor(v, 8, 64));
            v = fminf(v, __shfl_xor(v, 16, 64));
            if ((lane & 31) == 0)
                dst[rowbase + h2 * 32 + (q & 3) + 8 * (q >> 2) + 4 * half] = v;
        }
    }
}

__global__ __launch_bounds__(256) void reduce1(
        const float* __restrict__ minsP,
        const float* __restrict__ X, const float* __restrict__ Y,
        float2* __restrict__ out2) {
    __shared__ float s1[256], s2[256];
    int t = threadIdx.x;
    int i = blockIdx.x * 256 + t;           // RBLK*256 == NPTOT exactly
    float mx = 3.0e38f, my = 3.0e38f;
#pragma unroll
    for (int s = 0; s < NSEG; s++) {
        mx = fminf(mx, minsP[((size_t)s * 2 + 0) * NPTOT + i]);
        my = fminf(my, minsP[((size_t)s * 2 + 1) * NPTOT + i]);
    }
    float a = X[3*i], bb = X[3*i+1], c = X[3*i+2];
    float sx = mx + __fmaf_rn(a, a, __fmaf_rn(bb, bb, c * c));
    float d = Y[3*i], e = Y[3*i+1], f = Y[3*i+2];
    float sy = my + __fmaf_rn(d, d, __fmaf_rn(e, e, f * f));
    s1[t] = sx; s2[t] = sy;
    __syncthreads();
    for (int s = 128; s > 0; s >>= 1) {
        if (t < s) { s1[t] += s1[t + s]; s2[t] += s2[t + s]; }
        __syncthreads();
    }
    if (t == 0) out2[blockIdx.x] = make_float2(s1[0], s2[0]);
}

__global__ __launch_bounds__(RBLK) void reduce2(
        const float2* __restrict__ p2,
        const float* __restrict__ bpp, const float* __restrict__ lam,
        float* __restrict__ out) {
    __shared__ float s[RBLK];
    int t = threadIdx.x;
    float2 p = p2[t];
    s[t] = p.x + p.y;
    __syncthreads();
    for (int h = RBLK / 2; h > 0; h >>= 1) {
        if (t < h) s[t] += s[t + h];
        __syncthreads();
    }
    if (t == 0) out[0] = s[0] * (1.0f / (float)NPTOT) + lam[0] * bpp[0];
}

extern "C" void kernel_launch(void* const* d_in, const int* in_sizes, int n_in,
                              void* d_out, int out_size, void* d_ws, size_t ws_size,
                              hipStream_t stream) {
    const float* X   = (const float*)d_in[0];   // pc_pred  [4,8192,3]
    const float* Y   = (const float*)d_in[1];   // pc_target[4,8192,3]
    const float* bpp = (const float*)d_in[2];
    const float* lam = (const float*)d_in[3];
    float* out = (float*)d_out;

    char* w = (char*)d_ws;
    float2* p2    = (float2*)w;                 w += 1024;
    float*  minsP = (float*)w;                  w += (size_t)NSEG * 2 * NPTOT * sizeof(float);
    uint4*  Arec  = (uint4*)w;                  w += (size_t)2 * NPTOT * 2 * sizeof(uint4);
    uint4*  Brec  = (uint4*)w;

    prep<<<(2 * NPTOT + 255) / 256, 256, 0, stream>>>(X, Y, Arec, Brec);
    mfma_pass<<<1024, 256, 0, stream>>>(Arec, Brec, minsP);
    reduce1<<<RBLK, 256, 0, stream>>>(minsP, X, Y, p2);
    reduce2<<<1, RBLK, 0, stream>>>(p2, bpp, lam, out);
}